// Round 1
// baseline (693.853 us; speedup 1.0000x reference)
//
#include <hip/hip_runtime.h>
#include <cstdint>
#include <cstddef>

// Shapes fixed by setup_inputs()
#define GRP 16
#define KD  2048
#define ND  2048
#define TD  16384

#define BM 128
#define BN 128
#define BK 64
#define NT (KD / BK)

typedef __bf16 bf16x8 __attribute__((ext_vector_type(8)));
typedef float  f32x4  __attribute__((ext_vector_type(4)));

// RNE fp32->bf16 pair pack: result = bf(x) | (bf(y)<<16)
__device__ __forceinline__ uint32_t pk2bf(float x, float y) {
  uint32_t ux = __builtin_bit_cast(uint32_t, x);
  uint32_t uy = __builtin_bit_cast(uint32_t, y);
  ux += 0x7fffu + ((ux >> 16) & 1u);
  uy += 0x7fffu + ((uy >> 16) & 1u);
  // D bytes = [ux.b2, ux.b3, uy.b2, uy.b3]  (v_perm_b32: sel 0..3 -> S1(=ux), 4..7 -> S0(=uy))
  return __builtin_amdgcn_perm(uy, ux, 0x07060302);
}

__device__ __forceinline__ int find_group(const int* tokens, int row0) {
  int g = GRP - 1, start = 0;
  for (int i = 0; i < GRP; ++i) {
    int sz = tokens[i];
    if (row0 < start + sz) { g = i; break; }
    start += sz;
  }
  return g;
}

// Fully fused grouped GEMM:
//   A fp32 [T][K]  -- converted to bf16 while staging (reg->LDS)
//   W fp32 [G][K][N] -- converted AND transposed to [n][k] while staging
//   C fp32 [T][N]
// LDS tiles are [row][BK] bf16 with 16B chunks xor-swizzled by (row&7) so the
// MFMA fragment reads (16 lanes x 16 rows, same logical chunk) are conflict-free.
__global__ __launch_bounds__(256, 2)
void fused_gemm(const float* __restrict__ A, const float* __restrict__ W,
                const int* __restrict__ tokens, float* __restrict__ C) {
  __shared__ uint16_t Alds[BM * BK];   // 16 KiB
  __shared__ uint16_t Blds[BN * BK];   // 16 KiB

  const int t    = threadIdx.x;
  const int n0   = blockIdx.x * BN;
  const int row0 = blockIdx.y * BM;

  const int g = find_group(tokens, row0);
  const float* Wg = W + (size_t)g * KD * ND;

  const int lane = t & 63;
  const int wid  = t >> 6;
  const int wm   = wid & 1;
  const int wn   = wid >> 1;
  const int l16  = lane & 15;
  const int quad = lane >> 4;

  // ---- A staging geometry: 1024 chunks (8 bf16 = 16B each); thread owns c = t + 256*i ----
  // row r = c>>3, logical chunk cl = c&7 (k = cl*8..cl*8+7), phys chunk = cl ^ (r&7).
  // Per b128-write instruction: 8 lanes/row x all 8 phys chunks -> conflict-free.
  const float* aptr[4];
  uint32_t*    adst[4];
  for (int i = 0; i < 4; ++i) {
    const int c  = t + 256 * i;
    const int r  = c >> 3;
    const int cl = c & 7;
    aptr[i] = A + (size_t)(row0 + r) * KD + cl * 8;
    adst[i] = (uint32_t*)&Alds[(r * 8 + (cl ^ (r & 7))) * 8];
  }

  // ---- B staging geometry (transpose-on-the-fly) ----
  // Lane owns column n = n0 + (t&127); covers k-chunks kc = (t>>7)*4 + {0..3}.
  // Global loads: per (kc,j) instruction, 64 lanes contiguous in n -> 256B coalesced.
  // LDS write: row n, phys chunk kc^(n&7); n&7 spans 0..7 across lanes -> conflict-free.
  const int nl = t & 127;
  const int bh = t >> 7;
  const float* bptr = Wg + (size_t)(bh * 32) * ND + n0 + nl;
  uint32_t* bdst[4];
  for (int c = 0; c < 4; ++c) {
    const int kc = bh * 4 + c;
    bdst[c] = (uint32_t*)&Blds[(nl * 8 + (kc ^ (nl & 7))) * 8];
  }

  // ---- fragment LDS offsets (u16 units), both k-halves ----
  int aoff[2][4], boff[2][4];
  for (int h = 0; h < 2; ++h) {
    for (int mi = 0; mi < 4; ++mi) {
      const int r = wm * 64 + mi * 16 + l16;
      aoff[h][mi] = r * BK + (((h * 4 + quad) ^ (r & 7)) * 8);
    }
    for (int ni = 0; ni < 4; ++ni) {
      const int r = wn * 64 + ni * 16 + l16;
      boff[h][ni] = r * BK + (((h * 4 + quad) ^ (r & 7)) * 8);
    }
  }

  f32x4 acc[4][4] = {};

  // staging registers (held across the barrier: T14 async split)
  float4 ar[4][2];
  float  br[4][8];

  auto issue = [&](int k0) {
    #pragma unroll
    for (int i = 0; i < 4; ++i) {
      ar[i][0] = *(const float4*)(aptr[i] + k0);
      ar[i][1] = *(const float4*)(aptr[i] + k0 + 4);
    }
    const float* bp = bptr + (size_t)k0 * ND;
    #pragma unroll
    for (int c = 0; c < 4; ++c)
      #pragma unroll
      for (int j = 0; j < 8; ++j)
        br[c][j] = bp[(size_t)(c * 8 + j) * ND];
  };

  issue(0);

  for (int kt = 0; kt < NT; ++kt) {
    __syncthreads();   // previous tile's fragment reads done -> LDS reusable

    // convert + write A tile (4 x ds_write_b128)
    #pragma unroll
    for (int i = 0; i < 4; ++i) {
      uint4 p;
      p.x = pk2bf(ar[i][0].x, ar[i][0].y);
      p.y = pk2bf(ar[i][0].z, ar[i][0].w);
      p.z = pk2bf(ar[i][1].x, ar[i][1].y);
      p.w = pk2bf(ar[i][1].z, ar[i][1].w);
      *(uint4*)adst[i] = p;
    }
    // convert + write B tile, transposed (4 x ds_write_b128)
    #pragma unroll
    for (int c = 0; c < 4; ++c) {
      uint4 p;
      p.x = pk2bf(br[c][0], br[c][1]);
      p.y = pk2bf(br[c][2], br[c][3]);
      p.z = pk2bf(br[c][4], br[c][5]);
      p.w = pk2bf(br[c][6], br[c][7]);
      *(uint4*)bdst[c] = p;
    }

    // prefetch next K-tile into regs; loads stay in flight across the barrier
    // and complete under this tile's MFMA phase.
    if (kt + 1 < NT) issue((kt + 1) * BK);

    __syncthreads();   // staged tile visible

    #pragma unroll
    for (int h = 0; h < 2; ++h) {
      bf16x8 af[4], bfr[4];
      #pragma unroll
      for (int mi = 0; mi < 4; ++mi) af[mi]  = *(const bf16x8*)&Alds[aoff[h][mi]];
      #pragma unroll
      for (int ni = 0; ni < 4; ++ni) bfr[ni] = *(const bf16x8*)&Blds[boff[h][ni]];
      #pragma unroll
      for (int mi = 0; mi < 4; ++mi)
        #pragma unroll
        for (int ni = 0; ni < 4; ++ni)
          acc[mi][ni] = __builtin_amdgcn_mfma_f32_16x16x32_bf16(af[mi], bfr[ni],
                                                                acc[mi][ni], 0, 0, 0);
    }
  }

  // epilogue: C/D layout col=lane&15, row=quad*4+r (m89/m91-verified)
  #pragma unroll
  for (int mi = 0; mi < 4; ++mi) {
    const int m = row0 + wm * 64 + mi * 16 + quad * 4;
    #pragma unroll
    for (int ni = 0; ni < 4; ++ni) {
      const int n = n0 + wn * 64 + ni * 16 + l16;
      #pragma unroll
      for (int r = 0; r < 4; ++r)
        C[(size_t)(m + r) * ND + n] = acc[mi][ni][r];
    }
  }
}

extern "C" void kernel_launch(void* const* d_in, const int* in_sizes, int n_in,
                              void* d_out, int out_size, void* d_ws, size_t ws_size,
                              hipStream_t stream) {
  const float* hidden = (const float*)d_in[0];
  const float* weight = (const float*)d_in[1];
  const int*   tokens = (const int*)d_in[4];
  float* out = (float*)d_out;
  (void)d_ws; (void)ws_size;

  fused_gemm<<<dim3(ND / BN, TD / BM), 256, 0, stream>>>(hidden, weight, tokens, out);
}

// Round 2
// 644.867 us; speedup vs baseline: 1.0760x; 1.0760x over previous
//
#include <hip/hip_runtime.h>
#include <cstdint>
#include <cstddef>

// Shapes fixed by setup_inputs()
#define GRP 16
#define KD  2048
#define ND  2048
#define TD  16384

#define BM 128
#define BN 128
#define BK 64
#define NT (KD / BK)

typedef __bf16 bf16x8 __attribute__((ext_vector_type(8)));
typedef float  f32x4  __attribute__((ext_vector_type(4)));

__device__ __forceinline__ int find_group(const int* tokens, int row0) {
  int g = GRP - 1, start = 0;
  for (int i = 0; i < GRP; ++i) {
    int sz = tokens[i];
    if (row0 < start + sz) { g = i; break; }
    start += sz;
  }
  return g;
}

// fp32x8 -> bf16x8; plain casts let the compiler emit v_cvt_pk_bf16_f32 (RNE).
__device__ __forceinline__ bf16x8 cvt8(float4 a, float4 b) {
  bf16x8 v;
  v[0] = (__bf16)a.x; v[1] = (__bf16)a.y; v[2] = (__bf16)a.z; v[3] = (__bf16)a.w;
  v[4] = (__bf16)b.x; v[5] = (__bf16)b.y; v[6] = (__bf16)b.z; v[7] = (__bf16)b.w;
  return v;
}

// lgkmcnt(0) (ds_write visibility) -> raw s_barrier (NO vmcnt drain: prefetch
// loads stay in flight across the barrier) -> compiler memory fence so LDS
// reads of the new buffer are not hoisted above the barrier.
#define BAR() do {                                         \
    asm volatile("s_waitcnt lgkmcnt(0)" ::: "memory");     \
    __builtin_amdgcn_s_barrier();                          \
    asm volatile("" ::: "memory");                         \
  } while (0)

// Fully fused grouped GEMM, double-buffered LDS, one raw barrier per K-step.
//   A fp32 [T][K]  -> bf16 while staging (reg->LDS)
//   W fp32 [G][K][N] -> bf16 + transpose to [n][k] while staging
//   C fp32 [T][N]
// LDS tiles: [row][BK] bf16, 16B chunks xor-swizzled by (row&7) -> conflict-free
// ds_write_b128 staging and conflict-free MFMA fragment reads (round-1 verified).
__global__ __launch_bounds__(256, 2)
void fused_gemm(const float* __restrict__ A, const float* __restrict__ W,
                const int* __restrict__ tokens, float* __restrict__ C) {
  __shared__ uint16_t Alds[2][BM * BK];   // 2 x 16 KiB
  __shared__ uint16_t Blds[2][BN * BK];   // 2 x 16 KiB

  const int t    = threadIdx.x;
  const int n0   = blockIdx.x * BN;
  const int row0 = blockIdx.y * BM;

  const int g = find_group(tokens, row0);
  const float* Wg = W + (size_t)g * KD * ND;

  const int lane = t & 63;
  const int wid  = t >> 6;
  const int wm   = wid & 1;
  const int wn   = wid >> 1;
  const int l16  = lane & 15;
  const int quad = lane >> 4;

  // ---- A staging geometry: chunk c = t + 256*i; row r = c>>3, logical chunk
  // cl = c&7 (k = cl*8..cl*8+7), phys chunk = cl ^ (r&7). ----
  const float* aptr[4];
  int adst[4];                         // u16-unit offsets within a buffer
  #pragma unroll
  for (int i = 0; i < 4; ++i) {
    const int c  = t + 256 * i;
    const int r  = c >> 3;
    const int cl = c & 7;
    aptr[i] = A + (size_t)(row0 + r) * KD + cl * 8;
    adst[i] = (r * 8 + (cl ^ (r & 7))) * 8;
  }

  // ---- B staging geometry (transpose-on-the-fly): lane owns column n = t&127,
  // covers k-chunks kc = (t>>7)*4 + {0..3}; per-instruction global loads are
  // 64-lane contiguous in n (coalesced); ds_write_b128 at row n, phys chunk
  // kc^(n&7) -> spans all 8 chunk slots across lanes -> conflict-free. ----
  const int nl = t & 127;
  const int bh = t >> 7;
  const float* bbase = Wg + (size_t)(bh * 32) * ND + n0 + nl;
  int bdst[4];
  #pragma unroll
  for (int c = 0; c < 4; ++c) {
    const int kc = bh * 4 + c;
    bdst[c] = (nl * 8 + (kc ^ (nl & 7))) * 8;
  }

  // ---- fragment LDS offsets (u16 units), both k-halves ----
  int aoff[2][4], boff[2][4];
  #pragma unroll
  for (int h = 0; h < 2; ++h) {
    #pragma unroll
    for (int mi = 0; mi < 4; ++mi) {
      const int r = wm * 64 + mi * 16 + l16;
      aoff[h][mi] = r * BK + (((h * 4 + quad) ^ (r & 7)) * 8);
    }
    #pragma unroll
    for (int ni = 0; ni < 4; ++ni) {
      const int r = wn * 64 + ni * 16 + l16;
      boff[h][ni] = r * BK + (((h * 4 + quad) ^ (r & 7)) * 8);
    }
  }

  f32x4 acc[4][4] = {};

  // staging registers (one set; consumed by convert, refilled by next issue)
  float4 ar[4][2];
  float  br[4][8];

  auto issue = [&](int k0) {
    #pragma unroll
    for (int i = 0; i < 4; ++i) {
      ar[i][0] = *(const float4*)(aptr[i] + k0);
      ar[i][1] = *(const float4*)(aptr[i] + k0 + 4);
    }
    #pragma unroll
    for (int c = 0; c < 4; ++c)
      #pragma unroll
      for (int j = 0; j < 8; ++j)
        br[c][j] = bbase[(size_t)(k0 + c * 8 + j) * ND];
  };

  auto convert = [&](int buf) {
    #pragma unroll
    for (int i = 0; i < 4; ++i)
      *(bf16x8*)&Alds[buf][adst[i]] = cvt8(ar[i][0], ar[i][1]);
    #pragma unroll
    for (int c = 0; c < 4; ++c) {
      bf16x8 w;
      #pragma unroll
      for (int j = 0; j < 8; ++j) w[j] = (__bf16)br[c][j];
      *(bf16x8*)&Blds[buf][bdst[c]] = w;
    }
  };

  // prologue: tile 0 -> buf0; tile 1 loads in flight
  issue(0);
  convert(0);
  issue(BK);
  BAR();

  #pragma unroll 2
  for (int kt = 0; kt < NT; ++kt) {
    const int cur = kt & 1;
    const int nxt = cur ^ 1;

    // convert tile kt+1 (regs issued last iteration) into the other buffer;
    // then issue tile kt+2 -- those loads fly across MFMA + barrier.
    if (kt + 1 < NT) {
      convert(nxt);
      if (kt + 2 < NT) issue((kt + 2) * BK);
    }

    // MFMA on current buffer
    __builtin_amdgcn_s_setprio(1);
    #pragma unroll
    for (int h = 0; h < 2; ++h) {
      bf16x8 af[4], bfr[4];
      #pragma unroll
      for (int mi = 0; mi < 4; ++mi) af[mi]  = *(const bf16x8*)&Alds[cur][aoff[h][mi]];
      #pragma unroll
      for (int ni = 0; ni < 4; ++ni) bfr[ni] = *(const bf16x8*)&Blds[cur][boff[h][ni]];
      #pragma unroll
      for (int mi = 0; mi < 4; ++mi)
        #pragma unroll
        for (int ni = 0; ni < 4; ++ni)
          acc[mi][ni] = __builtin_amdgcn_mfma_f32_16x16x32_bf16(af[mi], bfr[ni],
                                                                acc[mi][ni], 0, 0, 0);
    }
    __builtin_amdgcn_s_setprio(0);

    BAR();
  }

  // epilogue: C/D layout col=lane&15, row=quad*4+r (m89/m91-verified)
  #pragma unroll
  for (int mi = 0; mi < 4; ++mi) {
    const int m = row0 + wm * 64 + mi * 16 + quad * 4;
    #pragma unroll
    for (int ni = 0; ni < 4; ++ni) {
      const int n = n0 + wn * 64 + ni * 16 + l16;
      #pragma unroll
      for (int r = 0; r < 4; ++r)
        C[(size_t)(m + r) * ND + n] = acc[mi][ni][r];
    }
  }
}

extern "C" void kernel_launch(void* const* d_in, const int* in_sizes, int n_in,
                              void* d_out, int out_size, void* d_ws, size_t ws_size,
                              hipStream_t stream) {
  const float* hidden = (const float*)d_in[0];
  const float* weight = (const float*)d_in[1];
  const int*   tokens = (const int*)d_in[4];
  float* out = (float*)d_out;
  (void)d_ws; (void)ws_size;

  fused_gemm<<<dim3(ND / BN, TD / BM), 256, 0, stream>>>(hidden, weight, tokens, out);
}

// Round 4
// 638.803 us; speedup vs baseline: 1.0862x; 1.0095x over previous
//
#include <hip/hip_runtime.h>
#include <cstdint>
#include <cstddef>

// Shapes fixed by setup_inputs()
#define GRP 16
#define KD  2048
#define ND  2048
#define TD  16384

#define BM 256
#define BN 256
#define BK 64
#define NTILE (KD / BK)   // 32 K-tiles, processed 2 per iteration

typedef __bf16 bf16x8 __attribute__((ext_vector_type(8)));
typedef float  f32x4  __attribute__((ext_vector_type(4)));

__device__ __forceinline__ uint16_t f2bf(float f) {
  uint32_t u = __builtin_bit_cast(uint32_t, f);
  u += 0x7fffu + ((u >> 16) & 1u);   // round-to-nearest-even
  return (uint16_t)(u >> 16);
}

__device__ __forceinline__ void gload16(const void* g, void* l) {
  __builtin_amdgcn_global_load_lds((__attribute__((address_space(1))) void*)g,
                                   (__attribute__((address_space(3))) void*)l,
                                   16, 0, 0);
}

__device__ __forceinline__ int find_group(const int* tokens, int row0) {
  int g = GRP - 1, start = 0;
  for (int i = 0; i < GRP; ++i) {
    int sz = tokens[i];
    if (row0 < start + sz) { g = i; break; }
    start += sz;
  }
  return g;
}

// ---------------- kernel 1: hidden fp32 -> bf16 (straight) ----------------
__global__ __launch_bounds__(256) void h2bf_kernel(const float* __restrict__ in,
                                                   uint16_t* __restrict__ out) {
  const size_t idx = ((size_t)blockIdx.x * 256 + threadIdx.x) * 8;
  const float4 a = *(const float4*)(in + idx);
  const float4 b = *(const float4*)(in + idx + 4);
  uint4 p;
  p.x = (uint32_t)f2bf(a.x) | ((uint32_t)f2bf(a.y) << 16);
  p.y = (uint32_t)f2bf(a.z) | ((uint32_t)f2bf(a.w) << 16);
  p.z = (uint32_t)f2bf(b.x) | ((uint32_t)f2bf(b.y) << 16);
  p.w = (uint32_t)f2bf(b.z) | ((uint32_t)f2bf(b.w) << 16);
  *(uint4*)(out + idx) = p;
}

// ------- kernel 2: weight fp32 [G][K][N] -> bf16 [G][N][K] (transpose) -----
__global__ __launch_bounds__(256) void wtrans_kernel(const float* __restrict__ w,
                                                     uint16_t* __restrict__ wT) {
  __shared__ uint32_t tile[64][33];   // [n][kpair], +1 u32 pad
  const int g  = blockIdx.z;
  const int n0 = blockIdx.x * 64;
  const int k0 = blockIdx.y * 64;
  const float* src = w + (size_t)g * KD * ND;
  uint16_t* dst = wT + (size_t)g * ND * KD;
  const int t = threadIdx.x;

  // phase 1: read 2 k-rows x 4 n, pack (k,k+1) bf16 pairs, vector ds_write_b32
  {
    const int k2 = t >> 4;          // k-pair index 0..15
    const int n4 = (t & 15) * 4;    // 0..60
    for (int half = 0; half < 2; ++half) {
      const int kp = half * 16 + k2;          // 0..31
      const int k  = kp * 2;
      const float4 v0 = *(const float4*)(src + (size_t)(k0 + k)     * ND + n0 + n4);
      const float4 v1 = *(const float4*)(src + (size_t)(k0 + k + 1) * ND + n0 + n4);
      tile[n4 + 0][kp] = (uint32_t)f2bf(v0.x) | ((uint32_t)f2bf(v1.x) << 16);
      tile[n4 + 1][kp] = (uint32_t)f2bf(v0.y) | ((uint32_t)f2bf(v1.y) << 16);
      tile[n4 + 2][kp] = (uint32_t)f2bf(v0.z) | ((uint32_t)f2bf(v1.z) << 16);
      tile[n4 + 3][kp] = (uint32_t)f2bf(v0.w) | ((uint32_t)f2bf(v1.w) << 16);
    }
  }
  __syncthreads();
  // phase 2: 2x ds_read_b128 per thread; consecutive lanes -> contiguous 16B
  {
    const int n  = t >> 2;
    const int kq = (t & 3) * 4;     // u32 units: 0,4,8,12
    const uint4 a = *(const uint4*)&tile[n][kq];
    const uint4 b = *(const uint4*)&tile[n][kq + 16];
    uint32_t* o = (uint32_t*)(dst + (size_t)(n0 + n) * KD + k0);
    *(uint4*)(o + kq)      = a;
    *(uint4*)(o + kq + 16) = b;
  }
}

// -------- kernel 3: grouped bf16 MFMA GEMM, 256x256 tile, 8-phase ----------
// Schedule (derived, slot-reuse-legal):
//   buffers: buf0 holds even K-tiles, buf1 odd. Iteration i computes tiles
//   2i (phases 0-3, buf0) and 2i+1 (phases 4-7, buf1).
//   Per-phase: frag ds_reads -> 1 half-tile stage (2 gload_lds) -> barrier ->
//   16 MFMA (setprio) -> lgkmcnt(0) -> [vmcnt at ph3/ph7] -> barrier.
//   Stage targets: ph0:A(b1,h0,2i+1) ph1:A(b1,h1,2i+1) ph2:B(b0,h0,2i+2)
//   ph3:B(b0,h1,2i+2) ph4:A(b0,h0,2i+2) ph5:A(b0,h1,2i+2) ph6:B(b1,h0,2i+3)
//   ph7:B(b1,h1,2i+3).
//   Legality: a stage at phase p targets a slot last ds_read at phase <= p-1;
//   that reader's lgkmcnt(0) precedes its phase-end barrier which precedes the
//   stage issue -> no LDS overwrite race. B-slot overwrite at ph2 is legal
//   because B fragments of the in-flight tile live in registers since ph0.
//   vmcnt(4) at end of ph3 confirms all stages through ph1 (A of tile 2i+1)
//   landed before the barrier that opens ph4; vmcnt(4) at end of ph7 confirms
//   through ph5 (A/B of tile 2i+2) before next iteration's ph0. The barrier
//   after the wait makes the guarantee block-wide (each wave waited its own
//   stages; all waves' stages therefore landed before any wave proceeds).
//   Peeled last pair uses vmcnt(0) at ph3 (nothing newer left flying).
__global__ __launch_bounds__(512, 2)
void gemm_kernel(const uint16_t* __restrict__ A, const uint16_t* __restrict__ Bt,
                 const int* __restrict__ tokens, float* __restrict__ C) {
  // [buf][half][r_local*64 + k] with 16B chunks xor-swizzled by (r_local&7)
  __shared__ uint16_t Alds[2][2][128 * 64];   // 64 KiB
  __shared__ uint16_t Blds[2][2][128 * 64];   // 64 KiB

  const int t = threadIdx.x;
  // XCD-aware swizzle: 512 blocks, 8 XCDs, 64 blocks/chunk; within a chunk
  // bx varies fastest -> 8x8 (by,bx) tiles share A-panels and group-B in L2.
  const int bid = blockIdx.x;
  const int swz = (bid & 7) * 64 + (bid >> 3);
  const int bx = swz & 7, by = swz >> 3;
  const int n0 = bx * BN, row0 = by * BM;

  const int g = find_group(tokens, row0);
  const uint16_t* Bg = Bt + (size_t)g * ND * KD;

  const int lane = t & 63, wid = t >> 6;
  const int wm = wid & 1;          // m-half owner: rows wm*128..wm*128+127
  const int wn = wid >> 1;         // n quarter: cols wn*64..wn*64+63
  const int l16 = lane & 15, quad = lane >> 4;

  // ---- staging geometry: chunk c = t + 512*j (j=0,1) covers one half-tile.
  // r = c>>3 (0..127 within half), phys chunk p = c&7 holds logical chunk
  // p^(r&7): gload_lds dest = linear c*16B; global src k pre-swizzled. ----
  const uint16_t* pA[2]; const uint16_t* pB[2];
  int doff[2];
  #pragma unroll
  for (int j = 0; j < 2; ++j) {
    const int c = t + 512 * j;
    const int r = c >> 3;
    const int ko = ((c & 7) ^ (r & 7)) * 8;
    pA[j] = A  + (size_t)(row0 + r) * KD + ko;
    pB[j] = Bg + (size_t)(n0  + r) * KD + ko;
    doff[j] = c * 8;                    // u16 units within [buf][half]
  }

  // ---- fragment LDS offsets (u16 units): row*64 + ((lchunk^(row&7))*8;
  // row&7 == l16&7 (row = mi*16+l16), so the xor term is mi-independent. ----
  int arow[8], brow[4], axk[2];
  #pragma unroll
  for (int mi = 0; mi < 8; ++mi) arow[mi] = (mi * 16 + l16) * 64;
  #pragma unroll
  for (int ni = 0; ni < 4; ++ni) brow[ni] = ((wn & 1) * 64 + ni * 16 + l16) * 64;
  #pragma unroll
  for (int kh = 0; kh < 2; ++kh) axk[kh] = ((kh * 4 + quad) ^ (l16 & 7)) * 8;

  const uint16_t* Abase[2] = { &Alds[0][wm][0],      &Alds[1][wm][0] };
  const uint16_t* Bbase[2] = { &Blds[0][wn >> 1][0], &Blds[1][wn >> 1][0] };

  f32x4 acc[8][4] = {};
  bf16x8 bfr[2][4];

#define STAGE_A(buf, half, T) do {                                              \
    gload16(pA[0] + (size_t)(half) * 128 * KD + (T) * BK, &Alds[buf][half][doff[0]]); \
    gload16(pA[1] + (size_t)(half) * 128 * KD + (T) * BK, &Alds[buf][half][doff[1]]); \
  } while (0)
#define STAGE_B(buf, half, T) do {                                              \
    gload16(pB[0] + (size_t)(half) * 128 * KD + (T) * BK, &Blds[buf][half][doff[0]]); \
    gload16(pB[1] + (size_t)(half) * 128 * KD + (T) * BK, &Blds[buf][half][doff[1]]); \
  } while (0)
#define NOSTAGE do {} while (0)
#define VM4 asm volatile("s_waitcnt vmcnt(4)" ::: "memory")
#define VM0 asm volatile("s_waitcnt vmcnt(0)" ::: "memory")
#define NOWAIT do {} while (0)
#define LGK0 asm volatile("s_waitcnt lgkmcnt(0)" ::: "memory")
#define BARRIER do { asm volatile("" ::: "memory");                             \
    __builtin_amdgcn_s_barrier(); asm volatile("" ::: "memory"); } while (0)

#define PHASE(buf, mib, DO_B, STAGE_STMT, ENDWAIT) do {                         \
    if (DO_B) {                                                                 \
      _Pragma("unroll") for (int kh2 = 0; kh2 < 2; ++kh2)                       \
        _Pragma("unroll") for (int ni2 = 0; ni2 < 4; ++ni2)                     \
          bfr[kh2][ni2] = *(const bf16x8*)&Bbase[buf][brow[ni2] + axk[kh2]];    \
    }                                                                           \
    bf16x8 af[2][2];                                                            \
    _Pragma("unroll") for (int kh2 = 0; kh2 < 2; ++kh2)                         \
      _Pragma("unroll") for (int m2 = 0; m2 < 2; ++m2)                          \
        af[kh2][m2] = *(const bf16x8*)&Abase[buf][arow[(mib) + m2] + axk[kh2]]; \
    STAGE_STMT;                                                                 \
    BARRIER;                                                                    \
    __builtin_amdgcn_s_setprio(1);                                              \
    _Pragma("unroll") for (int kh2 = 0; kh2 < 2; ++kh2)                         \
      _Pragma("unroll") for (int m2 = 0; m2 < 2; ++m2)                          \
        _Pragma("unroll") for (int ni2 = 0; ni2 < 4; ++ni2)                     \
          acc[(mib) + m2][ni2] = __builtin_amdgcn_mfma_f32_16x16x32_bf16(       \
              af[kh2][m2], bfr[kh2][ni2], acc[(mib) + m2][ni2], 0, 0, 0);       \
    __builtin_amdgcn_s_setprio(0);                                              \
    LGK0;                                                                       \
    ENDWAIT;                                                                    \
    BARRIER;                                                                    \
  } while (0)

  // prologue: tile 0 fully + tile 1's B; wait A0+B0 (leave B1's 4 flying)
  STAGE_B(0, 0, 0); STAGE_B(0, 1, 0);
  STAGE_A(0, 0, 0); STAGE_A(0, 1, 0);
  STAGE_B(1, 0, 1); STAGE_B(1, 1, 1);
  VM4;
  BARRIER;

  for (int i = 0; i < NTILE / 2 - 1; ++i) {   // i = 0..14, tiles 2i & 2i+1
    const int t1 = 2 * i + 1, t2 = 2 * i + 2, t3 = 2 * i + 3;
    PHASE(0, 0, true,  STAGE_A(1, 0, t1), NOWAIT);
    PHASE(0, 2, false, STAGE_A(1, 1, t1), NOWAIT);
    PHASE(0, 4, false, STAGE_B(0, 0, t2), NOWAIT);
    PHASE(0, 6, false, STAGE_B(0, 1, t2), VM4);
    PHASE(1, 0, true,  STAGE_A(0, 0, t2), NOWAIT);
    PHASE(1, 2, false, STAGE_A(0, 1, t2), NOWAIT);
    PHASE(1, 4, false, STAGE_B(1, 0, t3), NOWAIT);
    PHASE(1, 6, false, STAGE_B(1, 1, t3), VM4);
  }
  // peeled last pair: tiles 30 (buf0), 31 (buf1); only tile-31 A still to stage
  PHASE(0, 0, true,  STAGE_A(1, 0, NTILE - 1), NOWAIT);
  PHASE(0, 2, false, STAGE_A(1, 1, NTILE - 1), NOWAIT);
  PHASE(0, 4, false, NOSTAGE, NOWAIT);
  PHASE(0, 6, false, NOSTAGE, VM0);
  PHASE(1, 0, true,  NOSTAGE, NOWAIT);
  PHASE(1, 2, false, NOSTAGE, NOWAIT);
  PHASE(1, 4, false, NOSTAGE, NOWAIT);
  PHASE(1, 6, false, NOSTAGE, NOWAIT);

  // epilogue: C/D layout col=lane&15, row=quad*4+r (m89/m91-verified)
  #pragma unroll
  for (int mi = 0; mi < 8; ++mi) {
    const int m = row0 + wm * 128 + mi * 16 + quad * 4;
    #pragma unroll
    for (int ni = 0; ni < 4; ++ni) {
      const int n = n0 + wn * 64 + ni * 16 + l16;
      #pragma unroll
      for (int r = 0; r < 4; ++r)
        C[(size_t)(m + r) * ND + n] = acc[mi][ni][r];
    }
  }
}

// ------------- fallback: fp32 tiled GEMM (no workspace needed) -------------
__global__ __launch_bounds__(256) void fb_gemm(const float* __restrict__ A,
                                               const float* __restrict__ W,
                                               const int* __restrict__ tokens,
                                               float* __restrict__ C) {
  __shared__ float As[16][64];
  __shared__ float Bs[16][65];
  const int n0 = blockIdx.x * 64;
  const int m0 = blockIdx.y * 64;
  const int g = find_group(tokens, m0);
  const float* Wg = W + (size_t)g * KD * ND;
  const int tx = threadIdx.x & 15, ty = threadIdx.x >> 4;
  float acc[4][4] = {};
  for (int k0 = 0; k0 < KD; k0 += 16) {
    for (int e = threadIdx.x; e < 64 * 16; e += 256) {
      int m = e >> 4, k = e & 15;
      As[k][m] = A[(size_t)(m0 + m) * KD + k0 + k];
    }
    for (int e = threadIdx.x; e < 64 * 16; e += 256) {
      int n = e & 63, k = e >> 6;
      Bs[k][n] = Wg[(size_t)(k0 + k) * ND + n0 + n];
    }
    __syncthreads();
    for (int k = 0; k < 16; ++k)
      for (int i = 0; i < 4; ++i)
        for (int j = 0; j < 4; ++j)
          acc[i][j] += As[k][ty * 4 + i] * Bs[k][tx * 4 + j];
    __syncthreads();
  }
  for (int i = 0; i < 4; ++i)
    for (int j = 0; j < 4; ++j)
      C[(size_t)(m0 + ty * 4 + i) * ND + n0 + tx * 4 + j] = acc[i][j];
}

extern "C" void kernel_launch(void* const* d_in, const int* in_sizes, int n_in,
                              void* d_out, int out_size, void* d_ws, size_t ws_size,
                              hipStream_t stream) {
  const float* hidden = (const float*)d_in[0];
  const float* weight = (const float*)d_in[1];
  const int*   tokens = (const int*)d_in[4];
  float* out = (float*)d_out;

  const size_t needA = (size_t)TD * KD * 2;            // 64 MiB
  const size_t needB = (size_t)GRP * ND * KD * 2;      // 128 MiB

  if (ws_size >= needA + needB) {
    uint16_t* hB = (uint16_t*)d_ws;
    uint16_t* wT = (uint16_t*)((char*)d_ws + needA);
    h2bf_kernel<<<(int)(((size_t)TD * KD) / (256 * 8)), 256, 0, stream>>>(hidden, hB);
    wtrans_kernel<<<dim3(ND / 64, KD / 64, GRP), 256, 0, stream>>>(weight, wT);
    gemm_kernel<<<dim3(TD / BM * (ND / BN)), 512, 0, stream>>>(hB, wT, tokens, out);
  } else {
    fb_gemm<<<dim3(ND / 64, TD / 64), 256, 0, stream>>>(hidden, weight, tokens, out);
  }
}